// Round 2
// baseline (1458.690 us; speedup 1.0000x reference)
//
#include <hip/hip_runtime.h>

#define D 64

// ---------------------------------------------------------------------------
// Phase 1: per-node gate projections. One 64-lane wave per node.
// pack[v] = (s_dst[v] + gate_b, s_src[v], d[v], 0)
// ---------------------------------------------------------------------------
__global__ __launch_bounds__(256) void node_phase(
    const float* __restrict__ h,
    const float* __restrict__ deg,
    const float* __restrict__ gate_w,
    const float* __restrict__ gate_b,
    float4* __restrict__ pack,
    int n_nodes)
{
    int gtid = blockIdx.x * blockDim.x + threadIdx.x;
    int node = gtid >> 6;        // one wave (64 lanes) per node
    int lane = threadIdx.x & 63;
    if (node >= n_nodes) return;

    float hv = h[(size_t)node * D + lane];
    float pd = hv * gate_w[lane];        // contribution to s_dst
    float ps = hv * gate_w[D + lane];    // contribution to s_src

    // 64-lane butterfly reduce (both sums together)
    #pragma unroll
    for (int off = 32; off > 0; off >>= 1) {
        pd += __shfl_xor(pd, off);
        ps += __shfl_xor(ps, off);
    }

    if (lane == 0) {
        float4 v;
        v.x = pd + gate_b[0];
        v.y = ps;
        v.z = deg[node];
        v.w = 0.0f;
        pack[node] = v;
    }
}

// ---------------------------------------------------------------------------
// Phase 2: edge aggregation. 16 lanes per edge, float4 per lane.
// e = d_dst * d_src * tanh(s_dst[dst] + s_src[src] + b)
// z[dst] += h[src] * e   (hardware f32 atomics, no CAS loop)
// ---------------------------------------------------------------------------
__global__ __launch_bounds__(256) void edge_phase(
    const float4* __restrict__ h4,
    const int* __restrict__ src,
    const int* __restrict__ dst,
    const float4* __restrict__ pack,
    float* __restrict__ z,
    int n_edges)
{
    int gtid = blockIdx.x * blockDim.x + threadIdx.x;
    int e_id = gtid >> 4;        // 16 lanes per edge
    int lane = threadIdx.x & 15;
    if (e_id >= n_edges) return;

    int s = src[e_id];
    int t = dst[e_id];

    float4 np_t = pack[t];       // same addr across the 16-lane group -> broadcast
    float4 np_s = pack[s];

    float a = tanhf(np_t.x + np_s.y);      // gate_b already folded into .x
    float e = np_t.z * np_s.z * a;

    float4 hv = h4[(size_t)s * (D / 4) + lane];   // coalesced 256B row gather

    float* zp = z + (size_t)t * D + lane * 4;
    unsafeAtomicAdd(zp + 0, hv.x * e);
    unsafeAtomicAdd(zp + 1, hv.y * e);
    unsafeAtomicAdd(zp + 2, hv.z * e);
    unsafeAtomicAdd(zp + 3, hv.w * e);
}

extern "C" void kernel_launch(void* const* d_in, const int* in_sizes, int n_in,
                              void* d_out, int out_size, void* d_ws, size_t ws_size,
                              hipStream_t stream)
{
    const float* h   = (const float*)d_in[0];
    const float* deg = (const float*)d_in[1];
    const float* gw  = (const float*)d_in[2];
    const float* gb  = (const float*)d_in[3];
    const int*   src = (const int*)d_in[4];
    const int*   dst = (const int*)d_in[5];

    int n_nodes = in_sizes[1];
    int n_edges = in_sizes[4];

    float*  z    = (float*)d_out;
    float4* pack = (float4*)d_ws;   // n_nodes * 16 B = 1.6 MB scratch

    // z must start at zero (harness poisons d_out with 0xAA)
    hipMemsetAsync(d_out, 0, (size_t)n_nodes * D * sizeof(float), stream);

    {
        long long threads = (long long)n_nodes * 64;
        int blocks = (int)((threads + 255) / 256);
        node_phase<<<blocks, 256, 0, stream>>>(h, deg, gw, gb, pack, n_nodes);
    }
    {
        long long threads = (long long)n_edges * 16;
        int blocks = (int)((threads + 255) / 256);
        edge_phase<<<blocks, 256, 0, stream>>>((const float4*)h, src, dst, pack, z, n_edges);
    }
}

// Round 3
// 307.884 us; speedup vs baseline: 4.7378x; 4.7378x over previous
//
#include <hip/hip_runtime.h>

#define D 64

// ---------------------------------------------------------------------------
// Phase 1: per-node gate projections. One 64-lane wave per node.
// pack[v] = (s_dst[v] + gate_b, s_src[v], d[v], 0)
// ---------------------------------------------------------------------------
__global__ __launch_bounds__(256) void node_phase(
    const float* __restrict__ h,
    const float* __restrict__ deg,
    const float* __restrict__ gate_w,
    const float* __restrict__ gate_b,
    float4* __restrict__ pack,
    int n_nodes)
{
    int gtid = blockIdx.x * blockDim.x + threadIdx.x;
    int node = gtid >> 6;
    int lane = threadIdx.x & 63;
    if (node >= n_nodes) return;

    float hv = h[(size_t)node * D + lane];
    float pd = hv * gate_w[lane];
    float ps = hv * gate_w[D + lane];

    #pragma unroll
    for (int off = 32; off > 0; off >>= 1) {
        pd += __shfl_xor(pd, off);
        ps += __shfl_xor(ps, off);
    }

    if (lane == 0) {
        float4 v;
        v.x = pd + gate_b[0];
        v.y = ps;
        v.z = deg[node];
        v.w = 0.0f;
        pack[node] = v;
    }
}

// ---------------------------------------------------------------------------
// CSR build: histogram of dst
// ---------------------------------------------------------------------------
__global__ __launch_bounds__(256) void hist_kernel(
    const int* __restrict__ dst, int* __restrict__ counts, int n_edges)
{
    int e = blockIdx.x * blockDim.x + threadIdx.x;
    if (e < n_edges) atomicAdd(&counts[dst[e]], 1);
}

// Per-256-block exclusive scan; emits block totals.
__global__ __launch_bounds__(256) void scan_blocks(
    const int* __restrict__ counts, int* __restrict__ excl,
    int* __restrict__ block_sums, int n)
{
    __shared__ int sm[256];
    int i = blockIdx.x * 256 + threadIdx.x;
    int v = (i < n) ? counts[i] : 0;
    int orig = v;
    sm[threadIdx.x] = v;
    __syncthreads();
    for (int off = 1; off < 256; off <<= 1) {
        int add = (threadIdx.x >= (unsigned)off) ? sm[threadIdx.x - off] : 0;
        __syncthreads();
        sm[threadIdx.x] += add;
        __syncthreads();
    }
    if (i < n) excl[i] = sm[threadIdx.x] - orig;
    if (threadIdx.x == 255) block_sums[blockIdx.x] = sm[255];
}

// Single-block exclusive scan of block sums (nb <= 512).
__global__ __launch_bounds__(512) void scan_sums(int* __restrict__ block_sums, int nb)
{
    __shared__ int sm[512];
    int v = (threadIdx.x < (unsigned)nb) ? block_sums[threadIdx.x] : 0;
    int orig = v;
    sm[threadIdx.x] = v;
    __syncthreads();
    for (int off = 1; off < 512; off <<= 1) {
        int add = (threadIdx.x >= (unsigned)off) ? sm[threadIdx.x - off] : 0;
        __syncthreads();
        sm[threadIdx.x] += add;
        __syncthreads();
    }
    if (threadIdx.x < (unsigned)nb) block_sums[threadIdx.x] = sm[threadIdx.x] - orig;
}

__global__ __launch_bounds__(256) void add_offsets(
    const int* __restrict__ excl, const int* __restrict__ block_sums,
    int* __restrict__ offsets, int* __restrict__ cursor, int n, int total)
{
    int i = blockIdx.x * 256 + threadIdx.x;
    if (i < n) {
        int off = excl[i] + block_sums[i >> 8];
        offsets[i] = off;
        cursor[i]  = off;
        if (i == n - 1) offsets[n] = total;
    }
}

// ---------------------------------------------------------------------------
// Scatter edges into CSR order; precompute edge weight w.
// pairs[pos] = (src, bitcast(w))
// ---------------------------------------------------------------------------
__global__ __launch_bounds__(256) void scatter_kernel(
    const int* __restrict__ src, const int* __restrict__ dst,
    const float4* __restrict__ pack, int* __restrict__ cursor,
    uint2* __restrict__ pairs, int n_edges)
{
    int e = blockIdx.x * blockDim.x + threadIdx.x;
    if (e >= n_edges) return;
    int s = src[e], t = dst[e];
    float4 pt = pack[t];
    float4 ps = pack[s];
    float a = tanhf(pt.x + ps.y);         // gate_b folded into pt.x
    float w = pt.z * ps.z * a;
    int pos = atomicAdd(&cursor[t], 1);
    pairs[pos] = make_uint2((unsigned)s, __float_as_uint(w));
}

// ---------------------------------------------------------------------------
// Gather aggregation: one 64-lane wave per node.
// lane = slot(2b) * 16 + chunk(4b): 4 edges in flight x 16 float4 chunks.
// ---------------------------------------------------------------------------
__global__ __launch_bounds__(256) void aggregate_kernel(
    const float4* __restrict__ h4, const uint2* __restrict__ pairs,
    const int* __restrict__ offsets, float4* __restrict__ z4, int n_nodes)
{
    int gtid = blockIdx.x * blockDim.x + threadIdx.x;
    int node = gtid >> 6;
    if (node >= n_nodes) return;
    int lane  = threadIdx.x & 63;
    int slot  = lane >> 4;
    int chunk = lane & 15;

    int beg = offsets[node];
    int end = offsets[node + 1];

    float4 acc = make_float4(0.f, 0.f, 0.f, 0.f);
    for (int i = beg + slot; i < end; i += 4) {
        uint2 p = pairs[i];
        float w = __uint_as_float(p.y);
        float4 hv = h4[(size_t)p.x * (D / 4) + chunk];
        acc.x += hv.x * w;
        acc.y += hv.y * w;
        acc.z += hv.z * w;
        acc.w += hv.w * w;
    }

    // reduce across the 4 slots (lanes differing in bits 4,5)
    #pragma unroll
    for (int off = 16; off <= 32; off <<= 1) {
        acc.x += __shfl_xor(acc.x, off);
        acc.y += __shfl_xor(acc.y, off);
        acc.z += __shfl_xor(acc.z, off);
        acc.w += __shfl_xor(acc.w, off);
    }

    if (slot == 0) z4[(size_t)node * (D / 4) + chunk] = acc;
}

// ---------------------------------------------------------------------------
// Fallback (ws too small): direct atomic aggregation (round-2 kernel).
// ---------------------------------------------------------------------------
__global__ __launch_bounds__(256) void edge_phase_atomic(
    const float4* __restrict__ h4,
    const int* __restrict__ src, const int* __restrict__ dst,
    const float4* __restrict__ pack, float* __restrict__ z, int n_edges)
{
    int gtid = blockIdx.x * blockDim.x + threadIdx.x;
    int e_id = gtid >> 4;
    int lane = threadIdx.x & 15;
    if (e_id >= n_edges) return;
    int s = src[e_id], t = dst[e_id];
    float4 pt = pack[t], ps = pack[s];
    float a = tanhf(pt.x + ps.y);
    float e = pt.z * ps.z * a;
    float4 hv = h4[(size_t)s * (D / 4) + lane];
    float* zp = z + (size_t)t * D + lane * 4;
    unsafeAtomicAdd(zp + 0, hv.x * e);
    unsafeAtomicAdd(zp + 1, hv.y * e);
    unsafeAtomicAdd(zp + 2, hv.z * e);
    unsafeAtomicAdd(zp + 3, hv.w * e);
}

extern "C" void kernel_launch(void* const* d_in, const int* in_sizes, int n_in,
                              void* d_out, int out_size, void* d_ws, size_t ws_size,
                              hipStream_t stream)
{
    const float* h   = (const float*)d_in[0];
    const float* deg = (const float*)d_in[1];
    const float* gw  = (const float*)d_in[2];
    const float* gb  = (const float*)d_in[3];
    const int*   src = (const int*)d_in[4];
    const int*   dst = (const int*)d_in[5];

    int n_nodes = in_sizes[1];
    int n_edges = in_sizes[4];
    int nb      = (n_nodes + 255) / 256;   // scan blocks (391 <= 512)

    float* z = (float*)d_out;

    // --- workspace layout (aligned 256B regions) ---
    auto align = [](size_t x) { return (x + 255) & ~(size_t)255; };
    size_t pack_b   = align((size_t)n_nodes * sizeof(float4));
    size_t pairs_b  = align((size_t)n_edges * sizeof(uint2));
    size_t counts_b = align((size_t)n_nodes * sizeof(int));
    size_t excl_b   = align((size_t)n_nodes * sizeof(int));
    size_t offs_b   = align(((size_t)n_nodes + 1) * sizeof(int));
    size_t curs_b   = align((size_t)n_nodes * sizeof(int));
    size_t bsum_b   = align((size_t)nb * sizeof(int));
    size_t need = pack_b + pairs_b + counts_b + excl_b + offs_b + curs_b + bsum_b;

    char* base = (char*)d_ws;
    float4* pack    = (float4*)base;                 base += pack_b;
    uint2*  pairs   = (uint2*)base;                  base += pairs_b;
    int*    counts  = (int*)base;                    base += counts_b;
    int*    excl    = (int*)base;                    base += excl_b;
    int*    offsets = (int*)base;                    base += offs_b;
    int*    cursor  = (int*)base;                    base += curs_b;
    int*    bsums   = (int*)base;

    // node phase (needed by both paths)
    {
        long long threads = (long long)n_nodes * 64;
        int blocks = (int)((threads + 255) / 256);
        node_phase<<<blocks, 256, 0, stream>>>(h, deg, gw, gb, pack, n_nodes);
    }

    if (ws_size < need) {
        // fallback: atomic scatter-add
        hipMemsetAsync(d_out, 0, (size_t)n_nodes * D * sizeof(float), stream);
        long long threads = (long long)n_edges * 16;
        int blocks = (int)((threads + 255) / 256);
        edge_phase_atomic<<<blocks, 256, 0, stream>>>((const float4*)h, src, dst, pack, z, n_edges);
        return;
    }

    // CSR build
    hipMemsetAsync(counts, 0, (size_t)n_nodes * sizeof(int), stream);
    {
        int blocks = (n_edges + 255) / 256;
        hist_kernel<<<blocks, 256, 0, stream>>>(dst, counts, n_edges);
    }
    scan_blocks<<<nb, 256, 0, stream>>>(counts, excl, bsums, n_nodes);
    scan_sums<<<1, 512, 0, stream>>>(bsums, nb);
    add_offsets<<<nb, 256, 0, stream>>>(excl, bsums, offsets, cursor, n_nodes, n_edges);
    {
        int blocks = (n_edges + 255) / 256;
        scatter_kernel<<<blocks, 256, 0, stream>>>(src, dst, pack, cursor, pairs, n_edges);
    }
    // gather aggregation (no f32 atomics, coalesced z writes)
    {
        long long threads = (long long)n_nodes * 64;
        int blocks = (int)((threads + 255) / 256);
        aggregate_kernel<<<blocks, 256, 0, stream>>>((const float4*)h, pairs, offsets, (float4*)z, n_nodes);
    }
}